// Round 4
// baseline (980.346 us; speedup 1.0000x reference)
//
#include <hip/hip_runtime.h>
#include <hip/hip_bf16.h>

// ---------------------------------------------------------------------------
// Persistent fused kernel: x=(x_c+x_t) -> QKV (bf16 MFMA) -> per-token 8x8
// cross-head attention -> Wo projection -> fp32 NCHW out.
// 512 persistent blocks (2/CU), each pipelines 8 tiles of T=32 tokens:
// X(i+1) register-prefetch issued under tile i's compute; output stored as
// full 128B lines via wave-private LDS transpose.
// ---------------------------------------------------------------------------

typedef unsigned short u16;
typedef __bf16 bf16x8 __attribute__((ext_vector_type(8)));
typedef float f32x4 __attribute__((ext_vector_type(4)));
typedef unsigned short u16x8 __attribute__((ext_vector_type(8)));
typedef unsigned short u16x4 __attribute__((ext_vector_type(4)));

constexpr int CH = 256;        // channels
constexpr int HWN = 16384;     // H*W
constexpr int T = 32;          // tokens per tile
constexpr int LDXe = 264;      // X/O row stride (elems): s=33==1 mod 32 -> <=2-way everywhere
constexpr int LQe  = 776;      // QKV row stride: s=97==1 -> attn reads conflict-free
constexpr int NBLK = 512;      // persistent blocks (2 per CU)
constexpr int NITER = (8 * HWN / T) / NBLK;   // 8 tiles per block

// ws byte layout
constexpr size_t WS_WQKV = 0;             // 768*256 u16
constexpr size_t WS_WO   = 393216;        // 256*256 u16
constexpr size_t WS_BIAS = 524288;        // 768 f32

__device__ __forceinline__ u16 f2bf(float f) {
    unsigned u = __builtin_bit_cast(unsigned, f);
    unsigned r = u + 0x7FFFu + ((u >> 16) & 1u);   // RNE
    return (u16)(r >> 16);
}
__device__ __forceinline__ float bf2f(u16 u) {
    return __builtin_bit_cast(float, (unsigned)u << 16);
}

// --- prep: permuted bf16 weights + permuted biases -------------------------
// row j of Wq' = row (j%32)*8 + j/32 of Wq  (head-inner -> head-outer fold)
__global__ void prep_kernel(const float* __restrict__ Wq, const float* __restrict__ Wk,
                            const float* __restrict__ Wv, const float* __restrict__ Wo,
                            const float* __restrict__ bq, const float* __restrict__ bk,
                            const float* __restrict__ bv,
                            u16* __restrict__ Wqkv_b, u16* __restrict__ Wo_b,
                            float* __restrict__ bias_qkv) {
    const int i = blockIdx.x;    // 0..767
    const int c = threadIdx.x;   // 0..255
    const int j = i & 255;
    const int p = ((j & 31) << 3) + (j >> 5);
    const float* Wsrc = (i < 256) ? Wq : (i < 512 ? Wk : Wv);
    const float* bsrc = (i < 256) ? bq : (i < 512 ? bk : bv);
    Wqkv_b[i * 256 + c] = f2bf(Wsrc[p * 256 + c]);
    if (i < 256) Wo_b[i * 256 + c] = f2bf(Wo[i * 256 + c]);
    if (c == 0) bias_qkv[i] = bsrc[p];
}

// --- persistent fused kernel ----------------------------------------------
__launch_bounds__(512, 4)
__global__ void fused_kernel(const float* __restrict__ x_c, const float* __restrict__ x_t,
                             const u16* __restrict__ Wqkv_b, const u16* __restrict__ Wo_b,
                             const float* __restrict__ bias_qkv, const float* __restrict__ bo,
                             float* __restrict__ out) {
    __shared__ u16 XT[T * LDXe];     // X tile, later O tile (X dead after QKV GEMM)
    __shared__ u16 QKVT[T * LQe];    // QKV tile, later per-wave fp32 store scratch

    const int tid = threadIdx.x;
    const int lane = tid & 63;
    const int wave = tid >> 6;       // 0..7
    const int l15 = lane & 15;
    const int l4 = lane >> 4;

    const int t2 = (tid & 15) * 2;   // token pair for staging
    const int cg = (tid >> 4) * 8;   // 8-channel group for staging

    float2 va[8], vb[8];             // register-prefetched X slabs

    // initial prefetch (tile = blockIdx.x)
    {
        const int tok0 = blockIdx.x * T;
        const size_t base = (size_t)(tok0 >> 14) * CH * HWN + (tok0 & (HWN - 1)) + t2;
        const float* pc = x_c + base + (size_t)cg * HWN;
        const float* pt = x_t + base + (size_t)cg * HWN;
#pragma unroll
        for (int j = 0; j < 8; ++j) {
            va[j] = *(const float2*)&pc[(size_t)j * HWN];
            vb[j] = *(const float2*)&pt[(size_t)j * HWN];
        }
    }

    for (int it = 0; it < NITER; ++it) {
        const int tile = it * NBLK + blockIdx.x;   // concurrent blocks -> consecutive tiles
        const int tok0 = tile * T;
        const int b = tok0 >> 14;
        const int hw0 = tok0 & (HWN - 1);

        // ---- ph0: prefetched X -> LDS (fused add + bf16 cast)
        {
            u16x8 r0, r1;
#pragma unroll
            for (int j = 0; j < 8; ++j) {
                r0[j] = f2bf(va[j].x + vb[j].x);
                r1[j] = f2bf(va[j].y + vb[j].y);
            }
            *(u16x8*)&XT[t2 * LDXe + cg] = r0;
            *(u16x8*)&XT[(t2 + 1) * LDXe + cg] = r1;
        }
        __syncthreads();

        // ---- ph1: issue next-tile prefetch, then QKV' = Wqkv' @ X
        if (it + 1 < NITER) {
            const int ntok0 = (tile + NBLK) * T;
            const size_t base = (size_t)(ntok0 >> 14) * CH * HWN + (ntok0 & (HWN - 1)) + t2;
            const float* pc = x_c + base + (size_t)cg * HWN;
            const float* pt = x_t + base + (size_t)cg * HWN;
#pragma unroll
            for (int j = 0; j < 8; ++j) {
                va[j] = *(const float2*)&pc[(size_t)j * HWN];
                vb[j] = *(const float2*)&pt[(size_t)j * HWN];
            }
        }
        {
            const int m_base = wave * 96;          // 6 m-tiles of 16 rows
            f32x4 acc[6][2];
#pragma unroll
            for (int i = 0; i < 6; ++i)
#pragma unroll
                for (int j = 0; j < 2; ++j) acc[i][j] = (f32x4){0.f, 0.f, 0.f, 0.f};

#pragma unroll
            for (int kk = 0; kk < 8; ++kk) {
                const int koff = kk * 32 + l4 * 8;
                bf16x8 bfr[2];
#pragma unroll
                for (int ct = 0; ct < 2; ++ct)
                    bfr[ct] = __builtin_bit_cast(bf16x8,
                        *(const u16x8*)&XT[(ct * 16 + l15) * LDXe + koff]);
#pragma unroll
                for (int mt = 0; mt < 6; ++mt) {
                    const bf16x8 afr = __builtin_bit_cast(bf16x8,
                        *(const u16x8*)&Wqkv_b[(m_base + mt * 16 + l15) * 256 + koff]);
#pragma unroll
                    for (int ct = 0; ct < 2; ++ct)
                        acc[mt][ct] = __builtin_amdgcn_mfma_f32_16x16x32_bf16(
                            afr, bfr[ct], acc[mt][ct], 0, 0, 0);
                }
            }
#pragma unroll
            for (int mt = 0; mt < 6; ++mt) {
                const int i0 = m_base + mt * 16 + l4 * 4;
                const f32x4 bias = *(const f32x4*)&bias_qkv[i0];
#pragma unroll
                for (int ct = 0; ct < 2; ++ct) {
                    const int t = ct * 16 + l15;
                    u16x4 pk;
#pragma unroll
                    for (int r = 0; r < 4; ++r) pk[r] = f2bf(acc[mt][ct][r] + bias[r]);
                    *(u16x4*)&QKVT[t * LQe + i0] = pk;
                }
            }
        }
        __syncthreads();

        // ---- ph2: per-token 8x8 cross-head attention (256 threads), O -> XT
        if (tid < T * 8) {
            const int t = tid >> 3;      // token 0..31
            const int h = tid & 7;       // head
            const u16* __restrict__ row = &QKVT[t * LQe];
            float q[32];
#pragma unroll
            for (int i = 0; i < 4; ++i) {
                const u16x8 v = *(const u16x8*)&row[h * 32 + i * 8];
#pragma unroll
                for (int e = 0; e < 8; ++e) q[i * 8 + e] = bf2f(v[e]);
            }
            float w8[8];
#pragma unroll
            for (int g = 0; g < 8; ++g) {
                float s = 0.f;
#pragma unroll
                for (int i = 0; i < 4; ++i) {
                    const u16x8 v = *(const u16x8*)&row[256 + g * 32 + i * 8];
#pragma unroll
                    for (int e = 0; e < 8; ++e) s += q[i * 8 + e] * bf2f(v[e]);
                }
                w8[g] = s * 0.17677669529663687f;   // 32^-0.5
            }
            float m = w8[0];
#pragma unroll
            for (int g = 1; g < 8; ++g) m = fmaxf(m, w8[g]);
            float ssum = 0.f;
#pragma unroll
            for (int g = 0; g < 8; ++g) { w8[g] = __expf(w8[g] - m); ssum += w8[g]; }
            const float rinv = 1.f / ssum;
#pragma unroll
            for (int g = 0; g < 8; ++g) w8[g] *= rinv;
            // PV in 8-channel chunks (low register peak)
#pragma unroll
            for (int i = 0; i < 4; ++i) {
                float o8[8];
#pragma unroll
                for (int e = 0; e < 8; ++e) o8[e] = 0.f;
#pragma unroll
                for (int g = 0; g < 8; ++g) {
                    const u16x8 v = *(const u16x8*)&row[512 + g * 32 + i * 8];
#pragma unroll
                    for (int e = 0; e < 8; ++e) o8[e] += w8[g] * bf2f(v[e]);
                }
                u16x8 pk;
#pragma unroll
                for (int e = 0; e < 8; ++e) pk[e] = f2bf(o8[e]);
                *(u16x8*)&XT[t * LDXe + h * 32 + i * 8] = pk;
            }
        }
        __syncthreads();

        // ---- ph3: OUT = Wo @ O^T + bo, full-line fp32 stores
        {
            const int m_base = wave * 32;
            f32x4 acc[2][2];
#pragma unroll
            for (int i = 0; i < 2; ++i)
#pragma unroll
                for (int j = 0; j < 2; ++j) acc[i][j] = (f32x4){0.f, 0.f, 0.f, 0.f};

#pragma unroll
            for (int kk = 0; kk < 8; ++kk) {
                const int koff = kk * 32 + l4 * 8;
                bf16x8 bfr[2];
#pragma unroll
                for (int ct = 0; ct < 2; ++ct)
                    bfr[ct] = __builtin_bit_cast(bf16x8,
                        *(const u16x8*)&XT[(ct * 16 + l15) * LDXe + koff]);
#pragma unroll
                for (int mt = 0; mt < 2; ++mt) {
                    const bf16x8 afr = __builtin_bit_cast(bf16x8,
                        *(const u16x8*)&Wo_b[(m_base + mt * 16 + l15) * 256 + koff]);
#pragma unroll
                    for (int ct = 0; ct < 2; ++ct)
                        acc[mt][ct] = __builtin_amdgcn_mfma_f32_16x16x32_bf16(
                            afr, bfr[ct], acc[mt][ct], 0, 0, 0);
                }
            }
            // wave-private transpose in dead QKV region: [16 ch][36 tok-pad] fp32
            float* __restrict__ sw = (float*)QKVT + wave * 1152;   // 2 x 576 per wave
            const size_t outbase = ((size_t)b * CH) << 14;
#pragma unroll
            for (int mt = 0; mt < 2; ++mt) {
                float* __restrict__ swm = sw + mt * 576;
#pragma unroll
                for (int ct = 0; ct < 2; ++ct)
#pragma unroll
                    for (int r = 0; r < 4; ++r)
                        swm[(l4 * 4 + r) * 36 + ct * 16 + l15] = acc[mt][ct][r];
                asm volatile("s_waitcnt lgkmcnt(0)" ::: "memory");
#pragma unroll
                for (int j = 0; j < 2; ++j) {
                    const int ch = (lane >> 3) + 8 * j;
                    const int c0 = m_base + mt * 16 + ch;
                    f32x4 v = *(const f32x4*)&swm[ch * 36 + (lane & 7) * 4];
                    const float bb = bo[c0];
                    v[0] += bb; v[1] += bb; v[2] += bb; v[3] += bb;
                    *(f32x4*)&out[outbase + ((size_t)c0 << 14) + hw0 + (lane & 7) * 4] = v;
                }
            }
        }
        __syncthreads();
    }
}

extern "C" void kernel_launch(void* const* d_in, const int* in_sizes, int n_in,
                              void* d_out, int out_size, void* d_ws, size_t ws_size,
                              hipStream_t stream) {
    const float* x_c = (const float*)d_in[0];
    const float* x_t = (const float*)d_in[1];
    const float* Wq = (const float*)d_in[2];
    const float* bq = (const float*)d_in[3];
    const float* Wk = (const float*)d_in[4];
    const float* bk = (const float*)d_in[5];
    const float* Wv = (const float*)d_in[6];
    const float* bv = (const float*)d_in[7];
    const float* Wo = (const float*)d_in[8];
    const float* bo = (const float*)d_in[9];
    float* out = (float*)d_out;
    char* ws = (char*)d_ws;

    u16* Wqkv_b = (u16*)(ws + WS_WQKV);
    u16* Wo_b = (u16*)(ws + WS_WO);
    float* bias_qkv = (float*)(ws + WS_BIAS);

    prep_kernel<<<768, 256, 0, stream>>>(Wq, Wk, Wv, Wo, bq, bk, bv,
                                         Wqkv_b, Wo_b, bias_qkv);
    fused_kernel<<<NBLK, 512, 0, stream>>>(x_c, x_t, Wqkv_b, Wo_b,
                                           bias_qkv, bo, out);
}

// Round 5
// 665.098 us; speedup vs baseline: 1.4740x; 1.4740x over previous
//
#include <hip/hip_runtime.h>
#include <hip/hip_bf16.h>

// ---------------------------------------------------------------------------
// Persistent fused kernel: x=(x_c+x_t) -> QKV (bf16 MFMA) -> per-token 8x8
// cross-head attention -> Wo projection -> fp32 NCHW out.
// 512 persistent blocks, each pipelines 8 tiles of T=32 tokens:
// X(i+1) register-prefetch issued under tile i's compute; output stored as
// full 128B lines via wave-private LDS transpose.
// R5 fix: __launch_bounds__(512,2) — R4's (512,4) capped VGPR at 64 and
// spilled the cross-barrier prefetch registers to scratch (5x HBM traffic).
// ---------------------------------------------------------------------------

typedef unsigned short u16;
typedef __bf16 bf16x8 __attribute__((ext_vector_type(8)));
typedef float f32x4 __attribute__((ext_vector_type(4)));
typedef unsigned short u16x8 __attribute__((ext_vector_type(8)));
typedef unsigned short u16x4 __attribute__((ext_vector_type(4)));

constexpr int CH = 256;        // channels
constexpr int HWN = 16384;     // H*W
constexpr int T = 32;          // tokens per tile
constexpr int LDXe = 264;      // X/O row stride (elems): s=33==1 mod 32 -> <=2-way everywhere
constexpr int LQe  = 776;      // QKV row stride: s=97==1 -> attn reads conflict-free
constexpr int NBLK = 512;      // persistent blocks
constexpr int NITER = (8 * HWN / T) / NBLK;   // 8 tiles per block

// ws byte layout
constexpr size_t WS_WQKV = 0;             // 768*256 u16
constexpr size_t WS_WO   = 393216;        // 256*256 u16
constexpr size_t WS_BIAS = 524288;        // 768 f32

__device__ __forceinline__ u16 f2bf(float f) {
    unsigned u = __builtin_bit_cast(unsigned, f);
    unsigned r = u + 0x7FFFu + ((u >> 16) & 1u);   // RNE
    return (u16)(r >> 16);
}
__device__ __forceinline__ float bf2f(u16 u) {
    return __builtin_bit_cast(float, (unsigned)u << 16);
}

// --- prep: permuted bf16 weights + permuted biases -------------------------
// row j of Wq' = row (j%32)*8 + j/32 of Wq  (head-inner -> head-outer fold)
__global__ void prep_kernel(const float* __restrict__ Wq, const float* __restrict__ Wk,
                            const float* __restrict__ Wv, const float* __restrict__ Wo,
                            const float* __restrict__ bq, const float* __restrict__ bk,
                            const float* __restrict__ bv,
                            u16* __restrict__ Wqkv_b, u16* __restrict__ Wo_b,
                            float* __restrict__ bias_qkv) {
    const int i = blockIdx.x;    // 0..767
    const int c = threadIdx.x;   // 0..255
    const int j = i & 255;
    const int p = ((j & 31) << 3) + (j >> 5);
    const float* Wsrc = (i < 256) ? Wq : (i < 512 ? Wk : Wv);
    const float* bsrc = (i < 256) ? bq : (i < 512 ? bk : bv);
    Wqkv_b[i * 256 + c] = f2bf(Wsrc[p * 256 + c]);
    if (i < 256) Wo_b[i * 256 + c] = f2bf(Wo[i * 256 + c]);
    if (c == 0) bias_qkv[i] = bsrc[p];
}

// --- persistent fused kernel ----------------------------------------------
__launch_bounds__(512, 2)
__global__ void fused_kernel(const float* __restrict__ x_c, const float* __restrict__ x_t,
                             const u16* __restrict__ Wqkv_b, const u16* __restrict__ Wo_b,
                             const float* __restrict__ bias_qkv, const float* __restrict__ bo,
                             float* __restrict__ out) {
    __shared__ u16 XT[T * LDXe];     // X tile, later O tile (X dead after QKV GEMM)
    __shared__ u16 QKVT[T * LQe];    // QKV tile, later per-wave fp32 store scratch

    const int tid = threadIdx.x;
    const int lane = tid & 63;
    const int wave = tid >> 6;       // 0..7
    const int l15 = lane & 15;
    const int l4 = lane >> 4;

    const int t2 = (tid & 15) * 2;   // token pair for staging
    const int cg = (tid >> 4) * 8;   // 8-channel group for staging

    float2 va[8], vb[8];             // register-prefetched X slabs

    // initial prefetch (tile = blockIdx.x)
    {
        const int tok0 = blockIdx.x * T;
        const size_t base = (size_t)(tok0 >> 14) * CH * HWN + (tok0 & (HWN - 1)) + t2;
        const float* pc = x_c + base + (size_t)cg * HWN;
        const float* pt = x_t + base + (size_t)cg * HWN;
#pragma unroll
        for (int j = 0; j < 8; ++j) {
            va[j] = *(const float2*)&pc[(size_t)j * HWN];
            vb[j] = *(const float2*)&pt[(size_t)j * HWN];
        }
    }

    for (int it = 0; it < NITER; ++it) {
        const int tile = it * NBLK + blockIdx.x;   // concurrent blocks -> consecutive tiles
        const int tok0 = tile * T;
        const int b = tok0 >> 14;
        const int hw0 = tok0 & (HWN - 1);

        // ---- ph0: prefetched X -> LDS (fused add + bf16 cast)
        {
            u16x8 r0, r1;
#pragma unroll
            for (int j = 0; j < 8; ++j) {
                r0[j] = f2bf(va[j].x + vb[j].x);
                r1[j] = f2bf(va[j].y + vb[j].y);
            }
            *(u16x8*)&XT[t2 * LDXe + cg] = r0;
            *(u16x8*)&XT[(t2 + 1) * LDXe + cg] = r1;
        }
        __syncthreads();

        // ---- ph1: issue next-tile prefetch, then QKV' = Wqkv' @ X
        if (it + 1 < NITER) {
            const int ntok0 = (tile + NBLK) * T;
            const size_t base = (size_t)(ntok0 >> 14) * CH * HWN + (ntok0 & (HWN - 1)) + t2;
            const float* pc = x_c + base + (size_t)cg * HWN;
            const float* pt = x_t + base + (size_t)cg * HWN;
#pragma unroll
            for (int j = 0; j < 8; ++j) {
                va[j] = *(const float2*)&pc[(size_t)j * HWN];
                vb[j] = *(const float2*)&pt[(size_t)j * HWN];
            }
        }
        {
            const int m_base = wave * 96;          // 6 m-tiles of 16 rows
            f32x4 acc[6][2];
#pragma unroll
            for (int i = 0; i < 6; ++i)
#pragma unroll
                for (int j = 0; j < 2; ++j) acc[i][j] = (f32x4){0.f, 0.f, 0.f, 0.f};

#pragma unroll
            for (int kk = 0; kk < 8; ++kk) {
                const int koff = kk * 32 + l4 * 8;
                bf16x8 bfr[2];
#pragma unroll
                for (int ct = 0; ct < 2; ++ct)
                    bfr[ct] = __builtin_bit_cast(bf16x8,
                        *(const u16x8*)&XT[(ct * 16 + l15) * LDXe + koff]);
#pragma unroll
                for (int mt = 0; mt < 6; ++mt) {
                    const bf16x8 afr = __builtin_bit_cast(bf16x8,
                        *(const u16x8*)&Wqkv_b[(m_base + mt * 16 + l15) * 256 + koff]);
#pragma unroll
                    for (int ct = 0; ct < 2; ++ct)
                        acc[mt][ct] = __builtin_amdgcn_mfma_f32_16x16x32_bf16(
                            afr, bfr[ct], acc[mt][ct], 0, 0, 0);
                }
            }
#pragma unroll
            for (int mt = 0; mt < 6; ++mt) {
                const int i0 = m_base + mt * 16 + l4 * 4;
                const f32x4 bias = *(const f32x4*)&bias_qkv[i0];
#pragma unroll
                for (int ct = 0; ct < 2; ++ct) {
                    const int t = ct * 16 + l15;
                    u16x4 pk;
#pragma unroll
                    for (int r = 0; r < 4; ++r) pk[r] = f2bf(acc[mt][ct][r] + bias[r]);
                    *(u16x4*)&QKVT[t * LQe + i0] = pk;
                }
            }
        }
        __syncthreads();

        // ---- ph2: per-token 8x8 cross-head attention (256 threads), O -> XT
        if (tid < T * 8) {
            const int t = tid >> 3;      // token 0..31
            const int h = tid & 7;       // head
            const u16* __restrict__ row = &QKVT[t * LQe];
            float q[32];
#pragma unroll
            for (int i = 0; i < 4; ++i) {
                const u16x8 v = *(const u16x8*)&row[h * 32 + i * 8];
#pragma unroll
                for (int e = 0; e < 8; ++e) q[i * 8 + e] = bf2f(v[e]);
            }
            float w8[8];
#pragma unroll
            for (int g = 0; g < 8; ++g) {
                float s = 0.f;
#pragma unroll
                for (int i = 0; i < 4; ++i) {
                    const u16x8 v = *(const u16x8*)&row[256 + g * 32 + i * 8];
#pragma unroll
                    for (int e = 0; e < 8; ++e) s += q[i * 8 + e] * bf2f(v[e]);
                }
                w8[g] = s * 0.17677669529663687f;   // 32^-0.5
            }
            float m = w8[0];
#pragma unroll
            for (int g = 1; g < 8; ++g) m = fmaxf(m, w8[g]);
            float ssum = 0.f;
#pragma unroll
            for (int g = 0; g < 8; ++g) { w8[g] = __expf(w8[g] - m); ssum += w8[g]; }
            const float rinv = 1.f / ssum;
#pragma unroll
            for (int g = 0; g < 8; ++g) w8[g] *= rinv;
            // PV in 8-channel chunks (low register peak)
#pragma unroll
            for (int i = 0; i < 4; ++i) {
                float o8[8];
#pragma unroll
                for (int e = 0; e < 8; ++e) o8[e] = 0.f;
#pragma unroll
                for (int g = 0; g < 8; ++g) {
                    const u16x8 v = *(const u16x8*)&row[512 + g * 32 + i * 8];
#pragma unroll
                    for (int e = 0; e < 8; ++e) o8[e] += w8[g] * bf2f(v[e]);
                }
                u16x8 pk;
#pragma unroll
                for (int e = 0; e < 8; ++e) pk[e] = f2bf(o8[e]);
                *(u16x8*)&XT[t * LDXe + h * 32 + i * 8] = pk;
            }
        }
        __syncthreads();

        // ---- ph3: OUT = Wo @ O^T + bo, full-line fp32 stores
        {
            const int m_base = wave * 32;
            f32x4 acc[2][2];
#pragma unroll
            for (int i = 0; i < 2; ++i)
#pragma unroll
                for (int j = 0; j < 2; ++j) acc[i][j] = (f32x4){0.f, 0.f, 0.f, 0.f};

#pragma unroll
            for (int kk = 0; kk < 8; ++kk) {
                const int koff = kk * 32 + l4 * 8;
                bf16x8 bfr[2];
#pragma unroll
                for (int ct = 0; ct < 2; ++ct)
                    bfr[ct] = __builtin_bit_cast(bf16x8,
                        *(const u16x8*)&XT[(ct * 16 + l15) * LDXe + koff]);
#pragma unroll
                for (int mt = 0; mt < 2; ++mt) {
                    const bf16x8 afr = __builtin_bit_cast(bf16x8,
                        *(const u16x8*)&Wo_b[(m_base + mt * 16 + l15) * 256 + koff]);
#pragma unroll
                    for (int ct = 0; ct < 2; ++ct)
                        acc[mt][ct] = __builtin_amdgcn_mfma_f32_16x16x32_bf16(
                            afr, bfr[ct], acc[mt][ct], 0, 0, 0);
                }
            }
            // wave-private transpose in dead QKV region: [16 ch][36 tok-pad] fp32
            float* __restrict__ sw = (float*)QKVT + wave * 1152;   // 2 x 576 per wave
            const size_t outbase = ((size_t)b * CH) << 14;
#pragma unroll
            for (int mt = 0; mt < 2; ++mt) {
                float* __restrict__ swm = sw + mt * 576;
#pragma unroll
                for (int ct = 0; ct < 2; ++ct)
#pragma unroll
                    for (int r = 0; r < 4; ++r)
                        swm[(l4 * 4 + r) * 36 + ct * 16 + l15] = acc[mt][ct][r];
                asm volatile("s_waitcnt lgkmcnt(0)" ::: "memory");
#pragma unroll
                for (int j = 0; j < 2; ++j) {
                    const int ch = (lane >> 3) + 8 * j;
                    const int c0 = m_base + mt * 16 + ch;
                    f32x4 v = *(const f32x4*)&swm[ch * 36 + (lane & 7) * 4];
                    const float bb = bo[c0];
                    v[0] += bb; v[1] += bb; v[2] += bb; v[3] += bb;
                    *(f32x4*)&out[outbase + ((size_t)c0 << 14) + hw0 + (lane & 7) * 4] = v;
                }
            }
        }
        __syncthreads();
    }
}

extern "C" void kernel_launch(void* const* d_in, const int* in_sizes, int n_in,
                              void* d_out, int out_size, void* d_ws, size_t ws_size,
                              hipStream_t stream) {
    const float* x_c = (const float*)d_in[0];
    const float* x_t = (const float*)d_in[1];
    const float* Wq = (const float*)d_in[2];
    const float* bq = (const float*)d_in[3];
    const float* Wk = (const float*)d_in[4];
    const float* bk = (const float*)d_in[5];
    const float* Wv = (const float*)d_in[6];
    const float* bv = (const float*)d_in[7];
    const float* Wo = (const float*)d_in[8];
    const float* bo = (const float*)d_in[9];
    float* out = (float*)d_out;
    char* ws = (char*)d_ws;

    u16* Wqkv_b = (u16*)(ws + WS_WQKV);
    u16* Wo_b = (u16*)(ws + WS_WO);
    float* bias_qkv = (float*)(ws + WS_BIAS);

    prep_kernel<<<768, 256, 0, stream>>>(Wq, Wk, Wv, Wo, bq, bk, bv,
                                         Wqkv_b, Wo_b, bias_qkv);
    fused_kernel<<<NBLK, 512, 0, stream>>>(x_c, x_t, Wqkv_b, Wo_b,
                                           bias_qkv, bo, out);
}